// Round 19
// baseline (78.102 us; speedup 1.0000x reference)
//
#include <hip/hip_runtime.h>
#include <hip/hip_bf16.h>
#include <math.h>

// Sizes
#define HH 4
#define BB 8
#define CC 64
#define RR 64
#define LL 2048
#define AA 8
#define HC 256   // H*C
#define EPS 1e-5f
#define CHP 266  // conv1 LDS row pad

typedef unsigned short ushort_t;
typedef __attribute__((ext_vector_type(8))) short short8;
typedef __attribute__((ext_vector_type(4))) float f32x4;

static __device__ __forceinline__ ushort_t f2bf(float x) {
    unsigned u = __float_as_uint(x);
    unsigned r = (u + 0x7FFF + ((u >> 16) & 1)) >> 16;
    return (ushort_t)r;
}
static __device__ __forceinline__ float bf2f(ushort_t h) {
    return __uint_as_float(((unsigned)h) << 16);
}
static __device__ __forceinline__ void pack8(const float* p, short8& hi, short8& lo) {
    float4 x0 = *(const float4*)p;
    float4 x1 = *(const float4*)(p + 4);
    float xs[8] = {x0.x, x0.y, x0.z, x0.w, x1.x, x1.y, x1.z, x1.w};
#pragma unroll
    for (int e = 0; e < 8; ++e) {
        ushort_t h = f2bf(xs[e]);
        hi[e] = (short)h;
        lo[e] = (short)f2bf(xs[e] - bf2f(h));
    }
}

// ---------------------------------------------------------------------------
// kABC: fused K/V GEMM (bf16 MFMA split-3) + banded softmax (halo-redundant)
// + banded correction XC + S-partials. l-tile 32.  [R18-verbatim]
// grid (33, 64): blockIdx.x = hb (32 = weight-prep), blockIdx.y = l-tile(32).
__global__ __launch_bounds__(256, 4) void kABC(const float* __restrict__ inp,
                                               const float* __restrict__ kw,
                                               const float* __restrict__ vw,
                                               const float* __restrict__ hidden,
                                               float* __restrict__ XC,
                                               float* __restrict__ Spart,
                                               const float* __restrict__ pw1,
                                               const float* __restrict__ g1,
                                               const float* __restrict__ m1,
                                               const float* __restrict__ v1,
                                               const float* __restrict__ bb1,
                                               const float* __restrict__ pw2,
                                               const float* __restrict__ g2,
                                               const float* __restrict__ m2,
                                               const float* __restrict__ v2,
                                               const float* __restrict__ bb2,
                                               const float* __restrict__ w1ca,
                                               ushort_t* __restrict__ wEb,
                                               ushort_t* __restrict__ wFb,
                                               float* __restrict__ biasE,
                                               float* __restrict__ biasF,
                                               float* __restrict__ w1T) {
    if (blockIdx.x == 32) {
        int tid = blockIdx.y * 256 + threadIdx.x;
        const int stride = 64 * 256;
        for (int idx = tid; idx < 4 * 24 * 64 * 8; idx += stride) {
            int j = idx & 7, lane = (idx >> 3) & 63, t2 = idx >> 9;
            int ks = t2 % 24, rg = t2 / 24;
            int r = rg * 16 + (lane & 15);
            int k = ks * 32 + (lane >> 4) * 8 + j;
            int tap = k >> 8, ch = k & 255;
            float inv = g1[r] * rsqrtf(v1[r] + EPS);
            wEb[idx] = f2bf(pw1[(r * 256 + ch) * 3 + tap] * inv);
        }
        for (int idx = tid; idx < 4 * 6 * 64 * 8; idx += stride) {
            int j = idx & 7, lane = (idx >> 3) & 63, t2 = idx >> 9;
            int ks = t2 % 6, rg = t2 / 6;
            int r = rg * 16 + (lane & 15);
            int k = ks * 32 + (lane >> 4) * 8 + j;
            int tap = k >> 6, c = k & 63;
            float inv = g2[r] * rsqrtf(v2[r] + EPS);
            wFb[idx] = f2bf(pw2[(r * 64 + c) * 3 + tap] * inv);
        }
        for (int idx = tid; idx < 320 * 8; idx += stride)
            w1T[idx] = w1ca[(idx & 7) * 320 + (idx >> 3)];
        if (tid < 64) {
            float inv1 = g1[tid] * rsqrtf(v1[tid] + EPS);
            biasE[tid] = bb1[tid] - m1[tid] * inv1;
            float inv2 = g2[tid] * rsqrtf(v2[tid] + EPS);
            biasF[tid] = bb2[tid] - m2[tid] * inv2;
        }
        return;
    }
    int hb = blockIdx.x;
    int h = hb >> 3;
    int b = hb & 7;
    int l0 = blockIdx.y * 32;
    __shared__ __align__(16) char shbuf[2 * 48 * 72 * 2];
    ushort_t (*xsT)[48][72] = (ushort_t (*)[48][72])shbuf;
    float (*k_s)[44] = (float (*)[44])shbuf;
    __shared__ float partial[4][36][5];
    __shared__ float dw_s[36][5];
    __shared__ float u_s[36];
    __shared__ float red_s[64];
    int t = threadIdx.x;
    int lane = t & 63, wv = t >> 6;
    int a = lane & 15, kg = lane >> 4;
    short8 ah[2][2], al[2][2];
    {
        const float* kwh = kw + h * 4096;
        const float* vwh = vw + h * 4096;
#pragma unroll
        for (int rtl = 0; rtl < 2; ++rtl) {
            int rt = wv * 2 + rtl;
            int row = rt * 16 + a;
            const float* base = (rt < 4) ? (kwh + row * 64) : (vwh + (row - 64) * 64);
#pragma unroll
            for (int ks = 0; ks < 2; ++ks)
                pack8(base + ks * 32 + kg * 8, ah[rtl][ks], al[rtl][ks]);
        }
    }
    {
        float xv[12];
#pragma unroll
        for (int it = 0; it < 12; ++it) {
            int idx = t + it * 256;
            int ch = idx / 48, j = idx % 48;
            int l = l0 - 4 + j;
            xv[it] = (j < 40 && l >= 0 && l < LL)
                   ? inp[(size_t)(hb * 64 + ch) * LL + l] : 0.f;
        }
#pragma unroll
        for (int it = 0; it < 12; ++it) {
            int idx = t + it * 256;
            int ch = idx / 48, j = idx % 48;
            ushort_t hi = f2bf(xv[it]);
            xsT[0][j][ch] = hi;
            xsT[1][j][ch] = f2bf(xv[it] - bf2f(hi));
        }
    }
    // prefetch QK's hidden loads across the MFMA phase
    float hh[16];
    {
        int l = l0 - 2 + lane;
        int lc = min(max(l, 0), LL - 1);
        const float* hp = hidden + (size_t)(b * 64 + wv * 16) * LL + lc;
#pragma unroll
        for (int i = 0; i < 16; ++i) hh[i] = hp[(size_t)i * LL];
    }
    __syncthreads();
    f32x4 acc[2][3] = {};
#pragma unroll
    for (int ks = 0; ks < 2; ++ks) {
#pragma unroll
        for (int ct = 0; ct < 3; ++ct) {
            short8 bhf = *(const short8*)&xsT[0][ct * 16 + a][ks * 32 + kg * 8];
            short8 blf = *(const short8*)&xsT[1][ct * 16 + a][ks * 32 + kg * 8];
#pragma unroll
            for (int rtl = 0; rtl < 2; ++rtl) {
                acc[rtl][ct] = __builtin_amdgcn_mfma_f32_16x16x32_bf16(ah[rtl][ks], bhf, acc[rtl][ct], 0, 0, 0);
                acc[rtl][ct] = __builtin_amdgcn_mfma_f32_16x16x32_bf16(ah[rtl][ks], blf, acc[rtl][ct], 0, 0, 0);
                acc[rtl][ct] = __builtin_amdgcn_mfma_f32_16x16x32_bf16(al[rtl][ks], bhf, acc[rtl][ct], 0, 0, 0);
            }
        }
    }
    __syncthreads();   // xsT dead; space becomes k_s
#pragma unroll
    for (int rtl = 0; rtl < 2; ++rtl) {
        int rt = wv * 2 + rtl;
        if (rt < 4) {
#pragma unroll
            for (int ct = 0; ct < 3; ++ct) {
                int j = ct * 16 + a;
#pragma unroll
                for (int reg = 0; reg < 4; ++reg) {
                    int row = rt * 16 + kg * 4 + reg;
                    if (j < 44) k_s[row][j] = acc[rtl][ct][reg];
                }
            }
        }
    }
    __syncthreads();
    if (lane < 36) {
        float acc5[5] = {};
#pragma unroll
        for (int i = 0; i < 16; ++i) {
            int r = wv * 16 + i;
            acc5[0] += hh[i] * k_s[r][lane];
            acc5[1] += hh[i] * k_s[r][lane + 1];
            acc5[2] += hh[i] * k_s[r][lane + 2];
            acc5[3] += hh[i] * k_s[r][lane + 3];
            acc5[4] += hh[i] * k_s[r][lane + 4];
        }
#pragma unroll
        for (int d = 0; d < 5; ++d) partial[wv][lane][d] = acc5[d];
    }
    __syncthreads();
    // merged: softmax (t<36) ∥ V-scatter (waves 2,3)
    if (t < 36) {
        int l = l0 - 2 + t;
        if (l < 0 || l >= LL) {
            u_s[t] = 0.f;
#pragma unroll
            for (int d = 0; d < 5; ++d) dw_s[t][d] = 0.f;
        } else {
            float raw[5];
            float mx = 0.f;
            int nv = 0;
#pragma unroll
            for (int d = 0; d < 5; ++d) {
                float s = partial[0][t][d] + partial[1][t][d]
                        + partial[2][t][d] + partial[3][t][d];
                int m = l + d - 2;
                bool valid = (m >= 0 && m < LL);
                raw[d] = valid ? s * 0.125f : -1e30f;
                if (valid) { nv++; mx = fmaxf(mx, raw[d]); }
            }
            float e0 = __expf(-mx);
            float Z = (float)(LL - nv) * e0;
            float w[5];
#pragma unroll
            for (int d = 0; d < 5; ++d) {
                float e = (raw[d] > -1e29f) ? __expf(raw[d] - mx) : 0.f;
                w[d] = e;
                Z += e;
            }
            float inv = 1.f / Z;
            float u = e0 * inv;
            u_s[t] = u;
#pragma unroll
            for (int d = 0; d < 5; ++d) dw_s[t][d] = w[d] * inv - u;
        }
    }
    if (wv >= 2) {
#pragma unroll
        for (int rtl = 0; rtl < 2; ++rtl) {
            int vr0 = (wv * 2 + rtl - 4) * 16 + kg * 4;
#pragma unroll
            for (int ct = 0; ct < 3; ++ct) {
                int j = ct * 16 + a;
#pragma unroll
                for (int reg = 0; reg < 4; ++reg) {
                    if (j >= 2 && j < 38) k_s[vr0 + reg][j] = acc[rtl][ct][reg];
                }
            }
        }
    }
    __syncthreads();
    if (wv >= 2) {
#pragma unroll
        for (int rtl = 0; rtl < 2; ++rtl) {
            int vr0 = (wv * 2 + rtl - 4) * 16 + kg * 4;
#pragma unroll
            for (int reg = 0; reg < 4; ++reg) {
                float s = 0.f;
#pragma unroll
                for (int ct = 0; ct < 3; ++ct) {
                    int j = ct * 16 + a;
                    if (j >= 4 && j < 36) s += acc[rtl][ct][reg] * u_s[j - 2];
                }
                s += __shfl_xor(s, 1);
                s += __shfl_xor(s, 2);
                s += __shfl_xor(s, 4);
                s += __shfl_xor(s, 8);
                if (a == 0) red_s[vr0 + reg] = s;
            }
        }
    }
    {
        int mm = t & 31;
        int cq = t >> 5;
#pragma unroll
        for (int it = 0; it < 8; ++it) {
            int c = it * 8 + cq;
            float xc = 0.f;
#pragma unroll
            for (int o = -2; o <= 2; ++o)
                xc += k_s[c][mm - o + 4] * dw_s[mm - o + 2][o + 2];
            XC[(size_t)(hb * 64 + c) * LL + l0 + mm] = xc;
        }
    }
    __syncthreads();
    if (t < 64)
        Spart[((size_t)hb * 64 + blockIdx.y) * 64 + t] = red_s[t];
}

// ---------------------------------------------------------------------------
// Kernel D: x = inp + xcorr + S; channel attention -> gate; write XG.
// grid (B, 32), block 512 (8 waves).
// R19: all 72 independent global loads (inp, XC, hidden) hoisted BEFORE the
// Spart reduction so their latency hides under the 64-load reduce chain.
__global__ __launch_bounds__(512) void kD(const float* __restrict__ inp,
                                          const float* __restrict__ hidden,
                                          const float* __restrict__ XC,
                                          const float* __restrict__ Spart,
                                          const float* __restrict__ w1T,
                                          const float* __restrict__ b1,
                                          const float* __restrict__ w2,
                                          const float* __restrict__ b2,
                                          float* __restrict__ XG) {
    int b = blockIdx.x;
    int m0 = blockIdx.y * 64;
    __shared__ float S2_s[256];
    __shared__ float partial[8][64][9];
    int t = threadIdx.x;
    int m = t & 63;
    int wv = t >> 6;
    int cb = __builtin_amdgcn_readfirstlane(wv * 8);
    // --- hoisted loads: inp+XC (32) and hidden (8) issued first ---
    float iv[4][8], cv[4][8];
#pragma unroll
    for (int h = 0; h < 4; ++h) {
#pragma unroll
        for (int cc = 0; cc < 8; ++cc) {
            size_t idx = (size_t)((h * 8 + b) * 64 + cb + cc) * LL + m0 + m;
            iv[h][cc] = inp[idx];
            cv[h][cc] = XC[idx];
        }
    }
    float hv[8];
#pragma unroll
    for (int i = 0; i < 8; ++i)
        hv[i] = hidden[(size_t)(b * 64 + cb + i) * LL + m0 + m];
    // --- Spart reduction (latency of the above hides under this chain) ---
    if (t < 256) {
        int hb = (t >> 6) * 8 + b;
        float s = 0.f;
#pragma unroll
        for (int q = 0; q < 64; ++q)
            s += Spart[((size_t)hb * 64 + q) * 64 + (t & 63)];
        S2_s[t] = s;
    }
    __syncthreads();
    float xr[4][8];
#pragma unroll
    for (int h = 0; h < 4; ++h) {
#pragma unroll
        for (int cc = 0; cc < 8; ++cc)
            xr[h][cc] = iv[h][cc] + cv[h][cc] + S2_s[h * 64 + cb + cc];
    }
    float acc2[8] = {};
#pragma unroll
    for (int h = 0; h < 4; ++h) {
#pragma unroll
        for (int cc = 0; cc < 8; ++cc) {
            const float* wp = w1T + (h * 64 + cb + cc) * 8;
            float xv = xr[h][cc];
#pragma unroll
            for (int o = 0; o < 8; ++o) acc2[o] += wp[o] * xv;
        }
    }
#pragma unroll
    for (int i = 0; i < 8; ++i) {
        const float* wp = w1T + (256 + cb + i) * 8;
#pragma unroll
        for (int o = 0; o < 8; ++o) acc2[o] += wp[o] * hv[i];
    }
#pragma unroll
    for (int o = 0; o < 8; ++o) partial[wv][m][o] = acc2[o];
    __syncthreads();
    float a[8];
#pragma unroll
    for (int o = 0; o < 8; ++o) {
        float v = b1[o];
#pragma unroll
        for (int p = 0; p < 8; ++p) v += partial[p][m][o];
        a[o] = fmaxf(v, 0.f);
    }
#pragma unroll
    for (int h = 0; h < 4; ++h) {
#pragma unroll
        for (int cc = 0; cc < 8; ++cc) {
            int ch = h * 64 + cb + cc;
            const float* wp = w2 + ch * 8;
            float g = b2[ch];
#pragma unroll
            for (int o = 0; o < 8; ++o) g += wp[o] * a[o];
            float gate = 1.f / (1.f + __expf(-g));
            XG[(size_t)(b * 256 + ch) * LL + m0 + m] = xr[h][cc] * gate;
        }
    }
}

// ---------------------------------------------------------------------------
// kConvM: conv1 (256 -> 64) + folded BN + ReLU via bf16 MFMA.
// grid (B, 128), block 256 (4 waves), l-tile 16.  [R18-verbatim]
__global__ __launch_bounds__(256) void kConvM(const float* __restrict__ XG,
                                              const ushort_t* __restrict__ wEb,
                                              const float* __restrict__ biasE,
                                              float* __restrict__ Y1) {
    int b = blockIdx.x;
    int l0 = blockIdx.y * 16;
    __shared__ ushort_t xts[2][18][CHP];
    __shared__ float bias_s[64];
    int t = threadIdx.x;
    if (t < 64) bias_s[t] = biasE[t];
    for (int q = t; q < 18 * 64; q += 256) {
        int row = q % 18;
        int ch0 = (q / 18) * 4;
        int l = l0 - 1 + row;
        bool v = (l >= 0 && l < LL);
        unsigned hp[2], lp[2];
#pragma unroll
        for (int p = 0; p < 2; ++p) {
            unsigned h2 = 0, l2 = 0;
#pragma unroll
            for (int i = 0; i < 2; ++i) {
                int ch = ch0 + p * 2 + i;
                float x = v ? XG[(size_t)(b * 256 + ch) * LL + l] : 0.f;
                ushort_t hi = f2bf(x);
                ushort_t lo = f2bf(x - bf2f(hi));
                h2 |= ((unsigned)hi) << (16 * i);
                l2 |= ((unsigned)lo) << (16 * i);
            }
            hp[p] = h2; lp[p] = l2;
        }
        *(unsigned*)&xts[0][row][ch0] = hp[0];
        *(unsigned*)&xts[0][row][ch0 + 2] = hp[1];
        *(unsigned*)&xts[1][row][ch0] = lp[0];
        *(unsigned*)&xts[1][row][ch0 + 2] = lp[1];
    }
    __syncthreads();
    int lane = t & 63;
    int wid = t >> 6;
    int a = lane & 15;
    int kg = lane >> 4;
    f32x4 acc = {};
    union U8 { unsigned u[4]; short8 s; };
#pragma unroll 4
    for (int ks = 0; ks < 24; ++ks) {
        int tap = ks >> 3;
        int ch0 = ((ks & 7) << 5) + (kg << 3);
        const ushort_t* ap = wEb + ((((size_t)wid * 24 + ks) * 64 + lane) << 3);
        short8 afr = *(const short8*)ap;
        int row = a + tap;
        const ushort_t* xh = &xts[0][row][ch0];
        const ushort_t* xl = &xts[1][row][ch0];
        U8 bh, bl;
#pragma unroll
        for (int qq = 0; qq < 4; ++qq) {
            bh.u[qq] = *(const unsigned*)(xh + 2 * qq);
            bl.u[qq] = *(const unsigned*)(xl + 2 * qq);
        }
        acc = __builtin_amdgcn_mfma_f32_16x16x32_bf16(afr, bh.s, acc, 0, 0, 0);
        acc = __builtin_amdgcn_mfma_f32_16x16x32_bf16(afr, bl.s, acc, 0, 0, 0);
    }
    {
        int m = a;
#pragma unroll
        for (int reg = 0; reg < 4; ++reg) {
            int r = wid * 16 + kg * 4 + reg;
            float y = acc[reg] + bias_s[r];
            Y1[(size_t)(b * 64 + r) * LL + l0 + m] = fmaxf(y, 0.f);
        }
    }
}

// ---------------------------------------------------------------------------
// kCM2: conv2 (64 -> 64) + folded BN + ReLU via bf16 MFMA.
// grid (B, 128), block 256 (4 waves), l-tile 16.  [R18-verbatim]
__global__ __launch_bounds__(256) void kCM2(const float* __restrict__ Y1,
                                            const ushort_t* __restrict__ wFb,
                                            const float* __restrict__ biasF,
                                            float* __restrict__ out) {
    int b = blockIdx.x;
    int l0 = blockIdx.y * 16;
    __shared__ ushort_t yts[2][18][70];
    __shared__ float bias_s[64];
    int t = threadIdx.x;
    if (t < 64) bias_s[t] = biasF[t];
    for (int q = t; q < 18 * 16; q += 256) {
        int row = q % 18;
        int c0 = (q / 18) * 4;
        int l = l0 - 1 + row;
        bool v = (l >= 0 && l < LL);
        unsigned hp[2], lp[2];
#pragma unroll
        for (int p = 0; p < 2; ++p) {
            unsigned h2 = 0, l2 = 0;
#pragma unroll
            for (int i = 0; i < 2; ++i) {
                int c = c0 + p * 2 + i;
                float x = v ? Y1[(size_t)(b * 64 + c) * LL + l] : 0.f;
                ushort_t hi = f2bf(x);
                ushort_t lo = f2bf(x - bf2f(hi));
                h2 |= ((unsigned)hi) << (16 * i);
                l2 |= ((unsigned)lo) << (16 * i);
            }
            hp[p] = h2; lp[p] = l2;
        }
        *(unsigned*)&yts[0][row][c0] = hp[0];
        *(unsigned*)&yts[0][row][c0 + 2] = hp[1];
        *(unsigned*)&yts[1][row][c0] = lp[0];
        *(unsigned*)&yts[1][row][c0 + 2] = lp[1];
    }
    __syncthreads();
    int lane = t & 63;
    int wid = t >> 6;
    int a = lane & 15;
    int kg = lane >> 4;
    f32x4 acc = {};
    union U8 { unsigned u[4]; short8 s; };
#pragma unroll
    for (int ks = 0; ks < 6; ++ks) {
        int tap = ks >> 1;
        int c0 = ((ks & 1) << 5) + (kg << 3);
        const ushort_t* ap = wFb + ((((size_t)wid * 6 + ks) * 64 + lane) << 3);
        short8 afr = *(const short8*)ap;
        int s = a + tap;
        const ushort_t* yh = &yts[0][s][c0];
        const ushort_t* yl = &yts[1][s][c0];
        U8 bh, bl;
#pragma unroll
        for (int qq = 0; qq < 4; ++qq) {
            bh.u[qq] = *(const unsigned*)(yh + 2 * qq);
            bl.u[qq] = *(const unsigned*)(yl + 2 * qq);
        }
        acc = __builtin_amdgcn_mfma_f32_16x16x32_bf16(afr, bh.s, acc, 0, 0, 0);
        acc = __builtin_amdgcn_mfma_f32_16x16x32_bf16(afr, bl.s, acc, 0, 0, 0);
    }
    {
        int m = a;
#pragma unroll
        for (int reg = 0; reg < 4; ++reg) {
            int r = wid * 16 + kg * 4 + reg;
            float y = acc[reg] + bias_s[r];
            out[(size_t)(b * 64 + r) * LL + l0 + m] = fmaxf(y, 0.f);
        }
    }
}

// ---------------------------------------------------------------------------
extern "C" void kernel_launch(void* const* d_in, const int* in_sizes, int n_in,
                              void* d_out, int out_size, void* d_ws, size_t ws_size,
                              hipStream_t stream) {
    (void)in_sizes; (void)n_in; (void)out_size; (void)ws_size;
    const float* inp    = (const float*)d_in[0];
    const float* hidden = (const float*)d_in[1];
    const float* key_w  = (const float*)d_in[2];
    const float* value_w= (const float*)d_in[3];
    const float* ca_w1  = (const float*)d_in[4];
    const float* ca_b1  = (const float*)d_in[5];
    const float* ca_w2  = (const float*)d_in[6];
    const float* ca_b2  = (const float*)d_in[7];
    const float* pw1    = (const float*)d_in[8];
    const float* bn1_g  = (const float*)d_in[9];
    const float* bn1_b  = (const float*)d_in[10];
    const float* bn1_m  = (const float*)d_in[11];
    const float* bn1_v  = (const float*)d_in[12];
    const float* pw2    = (const float*)d_in[13];
    const float* bn2_g  = (const float*)d_in[14];
    const float* bn2_b  = (const float*)d_in[15];
    const float* bn2_m  = (const float*)d_in[16];
    const float* bn2_v  = (const float*)d_in[17];

    float* ws = (float*)d_ws;
    const size_t KV = (size_t)HH * BB * CC * LL;     // 4,194,304 floats
    float* XG = ws;
    float* XC = ws + KV;                             // banded correction
    float* Spart = ws + 2 * KV;                      // 32*64*64 = 131072
    float* w1T   = Spart + 131072;                   // 2560
    float* biasE = w1T + 2560;                       // 64
    float* biasF = biasE + 64;                       // 64
    ushort_t* wEb = (ushort_t*)(biasF + 64);         // 49152 bf16
    ushort_t* wFb = (ushort_t*)(biasF + 64 + 24576); // 12288 bf16
    float* Y1 = XC;   // alias: XC dead after kD

    kABC<<<dim3(33, 64), 256, 0, stream>>>(inp, key_w, value_w, hidden,
                                           XC, Spart,
                                           pw1, bn1_g, bn1_m, bn1_v, bn1_b,
                                           pw2, bn2_g, bn2_m, bn2_v, bn2_b,
                                           ca_w1, wEb, wFb, biasE, biasF, w1T);
    kD<<<dim3(BB, LL / 64), 512, 0, stream>>>(inp, hidden, XC, Spart,
                                              w1T, ca_b1, ca_w2, ca_b2, XG);
    kConvM<<<dim3(BB, 128), 256, 0, stream>>>(XG, wEb, biasE, Y1);
    kCM2<<<dim3(BB, 128), 256, 0, stream>>>(Y1, wFb, biasF, (float*)d_out);
}

// Round 20
// 62.686 us; speedup vs baseline: 1.2459x; 1.2459x over previous
//
#include <hip/hip_runtime.h>
#include <hip/hip_bf16.h>
#include <math.h>

// Sizes
#define HH 4
#define BB 8
#define CC 64
#define RR 64
#define LL 2048
#define AA 8
#define HC 256   // H*C
#define EPS 1e-5f
#define CHP 266  // conv1 LDS row pad

typedef unsigned short ushort_t;
typedef __attribute__((ext_vector_type(8))) short short8;
typedef __attribute__((ext_vector_type(4))) float f32x4;

static __device__ __forceinline__ ushort_t f2bf(float x) {
    unsigned u = __float_as_uint(x);
    unsigned r = (u + 0x7FFF + ((u >> 16) & 1)) >> 16;
    return (ushort_t)r;
}
static __device__ __forceinline__ float bf2f(ushort_t h) {
    return __uint_as_float(((unsigned)h) << 16);
}
static __device__ __forceinline__ void pack8(const float* p, short8& hi, short8& lo) {
    float4 x0 = *(const float4*)p;
    float4 x1 = *(const float4*)(p + 4);
    float xs[8] = {x0.x, x0.y, x0.z, x0.w, x1.x, x1.y, x1.z, x1.w};
#pragma unroll
    for (int e = 0; e < 8; ++e) {
        ushort_t h = f2bf(xs[e]);
        hi[e] = (short)h;
        lo[e] = (short)f2bf(xs[e] - bf2f(h));
    }
}

// ---------------------------------------------------------------------------
// kABC: fused K/V GEMM (bf16 MFMA split-3) + banded softmax (halo-redundant)
// + banded correction XC + S-partials. l-tile 32.  [R18-verbatim]
// grid (33, 64): blockIdx.x = hb (32 = weight-prep), blockIdx.y = l-tile(32).
__global__ __launch_bounds__(256, 4) void kABC(const float* __restrict__ inp,
                                               const float* __restrict__ kw,
                                               const float* __restrict__ vw,
                                               const float* __restrict__ hidden,
                                               float* __restrict__ XC,
                                               float* __restrict__ Spart,
                                               const float* __restrict__ pw1,
                                               const float* __restrict__ g1,
                                               const float* __restrict__ m1,
                                               const float* __restrict__ v1,
                                               const float* __restrict__ bb1,
                                               const float* __restrict__ pw2,
                                               const float* __restrict__ g2,
                                               const float* __restrict__ m2,
                                               const float* __restrict__ v2,
                                               const float* __restrict__ bb2,
                                               const float* __restrict__ w1ca,
                                               ushort_t* __restrict__ wEb,
                                               ushort_t* __restrict__ wFb,
                                               float* __restrict__ biasE,
                                               float* __restrict__ biasF,
                                               float* __restrict__ w1T) {
    if (blockIdx.x == 32) {
        int tid = blockIdx.y * 256 + threadIdx.x;
        const int stride = 64 * 256;
        for (int idx = tid; idx < 4 * 24 * 64 * 8; idx += stride) {
            int j = idx & 7, lane = (idx >> 3) & 63, t2 = idx >> 9;
            int ks = t2 % 24, rg = t2 / 24;
            int r = rg * 16 + (lane & 15);
            int k = ks * 32 + (lane >> 4) * 8 + j;
            int tap = k >> 8, ch = k & 255;
            float inv = g1[r] * rsqrtf(v1[r] + EPS);
            wEb[idx] = f2bf(pw1[(r * 256 + ch) * 3 + tap] * inv);
        }
        for (int idx = tid; idx < 4 * 6 * 64 * 8; idx += stride) {
            int j = idx & 7, lane = (idx >> 3) & 63, t2 = idx >> 9;
            int ks = t2 % 6, rg = t2 / 6;
            int r = rg * 16 + (lane & 15);
            int k = ks * 32 + (lane >> 4) * 8 + j;
            int tap = k >> 6, c = k & 63;
            float inv = g2[r] * rsqrtf(v2[r] + EPS);
            wFb[idx] = f2bf(pw2[(r * 64 + c) * 3 + tap] * inv);
        }
        for (int idx = tid; idx < 320 * 8; idx += stride)
            w1T[idx] = w1ca[(idx & 7) * 320 + (idx >> 3)];
        if (tid < 64) {
            float inv1 = g1[tid] * rsqrtf(v1[tid] + EPS);
            biasE[tid] = bb1[tid] - m1[tid] * inv1;
            float inv2 = g2[tid] * rsqrtf(v2[tid] + EPS);
            biasF[tid] = bb2[tid] - m2[tid] * inv2;
        }
        return;
    }
    int hb = blockIdx.x;
    int h = hb >> 3;
    int b = hb & 7;
    int l0 = blockIdx.y * 32;
    __shared__ __align__(16) char shbuf[2 * 48 * 72 * 2];
    ushort_t (*xsT)[48][72] = (ushort_t (*)[48][72])shbuf;
    float (*k_s)[44] = (float (*)[44])shbuf;
    __shared__ float partial[4][36][5];
    __shared__ float dw_s[36][5];
    __shared__ float u_s[36];
    __shared__ float red_s[64];
    int t = threadIdx.x;
    int lane = t & 63, wv = t >> 6;
    int a = lane & 15, kg = lane >> 4;
    short8 ah[2][2], al[2][2];
    {
        const float* kwh = kw + h * 4096;
        const float* vwh = vw + h * 4096;
#pragma unroll
        for (int rtl = 0; rtl < 2; ++rtl) {
            int rt = wv * 2 + rtl;
            int row = rt * 16 + a;
            const float* base = (rt < 4) ? (kwh + row * 64) : (vwh + (row - 64) * 64);
#pragma unroll
            for (int ks = 0; ks < 2; ++ks)
                pack8(base + ks * 32 + kg * 8, ah[rtl][ks], al[rtl][ks]);
        }
    }
    {
        float xv[12];
#pragma unroll
        for (int it = 0; it < 12; ++it) {
            int idx = t + it * 256;
            int ch = idx / 48, j = idx % 48;
            int l = l0 - 4 + j;
            xv[it] = (j < 40 && l >= 0 && l < LL)
                   ? inp[(size_t)(hb * 64 + ch) * LL + l] : 0.f;
        }
#pragma unroll
        for (int it = 0; it < 12; ++it) {
            int idx = t + it * 256;
            int ch = idx / 48, j = idx % 48;
            ushort_t hi = f2bf(xv[it]);
            xsT[0][j][ch] = hi;
            xsT[1][j][ch] = f2bf(xv[it] - bf2f(hi));
        }
    }
    // prefetch QK's hidden loads across the MFMA phase
    float hh[16];
    {
        int l = l0 - 2 + lane;
        int lc = min(max(l, 0), LL - 1);
        const float* hp = hidden + (size_t)(b * 64 + wv * 16) * LL + lc;
#pragma unroll
        for (int i = 0; i < 16; ++i) hh[i] = hp[(size_t)i * LL];
    }
    __syncthreads();
    f32x4 acc[2][3] = {};
#pragma unroll
    for (int ks = 0; ks < 2; ++ks) {
#pragma unroll
        for (int ct = 0; ct < 3; ++ct) {
            short8 bhf = *(const short8*)&xsT[0][ct * 16 + a][ks * 32 + kg * 8];
            short8 blf = *(const short8*)&xsT[1][ct * 16 + a][ks * 32 + kg * 8];
#pragma unroll
            for (int rtl = 0; rtl < 2; ++rtl) {
                acc[rtl][ct] = __builtin_amdgcn_mfma_f32_16x16x32_bf16(ah[rtl][ks], bhf, acc[rtl][ct], 0, 0, 0);
                acc[rtl][ct] = __builtin_amdgcn_mfma_f32_16x16x32_bf16(ah[rtl][ks], blf, acc[rtl][ct], 0, 0, 0);
                acc[rtl][ct] = __builtin_amdgcn_mfma_f32_16x16x32_bf16(al[rtl][ks], bhf, acc[rtl][ct], 0, 0, 0);
            }
        }
    }
    __syncthreads();   // xsT dead; space becomes k_s
#pragma unroll
    for (int rtl = 0; rtl < 2; ++rtl) {
        int rt = wv * 2 + rtl;
        if (rt < 4) {
#pragma unroll
            for (int ct = 0; ct < 3; ++ct) {
                int j = ct * 16 + a;
#pragma unroll
                for (int reg = 0; reg < 4; ++reg) {
                    int row = rt * 16 + kg * 4 + reg;
                    if (j < 44) k_s[row][j] = acc[rtl][ct][reg];
                }
            }
        }
    }
    __syncthreads();
    if (lane < 36) {
        float acc5[5] = {};
#pragma unroll
        for (int i = 0; i < 16; ++i) {
            int r = wv * 16 + i;
            acc5[0] += hh[i] * k_s[r][lane];
            acc5[1] += hh[i] * k_s[r][lane + 1];
            acc5[2] += hh[i] * k_s[r][lane + 2];
            acc5[3] += hh[i] * k_s[r][lane + 3];
            acc5[4] += hh[i] * k_s[r][lane + 4];
        }
#pragma unroll
        for (int d = 0; d < 5; ++d) partial[wv][lane][d] = acc5[d];
    }
    __syncthreads();
    // merged: softmax (t<36) ∥ V-scatter (waves 2,3)
    if (t < 36) {
        int l = l0 - 2 + t;
        if (l < 0 || l >= LL) {
            u_s[t] = 0.f;
#pragma unroll
            for (int d = 0; d < 5; ++d) dw_s[t][d] = 0.f;
        } else {
            float raw[5];
            float mx = 0.f;
            int nv = 0;
#pragma unroll
            for (int d = 0; d < 5; ++d) {
                float s = partial[0][t][d] + partial[1][t][d]
                        + partial[2][t][d] + partial[3][t][d];
                int m = l + d - 2;
                bool valid = (m >= 0 && m < LL);
                raw[d] = valid ? s * 0.125f : -1e30f;
                if (valid) { nv++; mx = fmaxf(mx, raw[d]); }
            }
            float e0 = __expf(-mx);
            float Z = (float)(LL - nv) * e0;
            float w[5];
#pragma unroll
            for (int d = 0; d < 5; ++d) {
                float e = (raw[d] > -1e29f) ? __expf(raw[d] - mx) : 0.f;
                w[d] = e;
                Z += e;
            }
            float inv = 1.f / Z;
            float u = e0 * inv;
            u_s[t] = u;
#pragma unroll
            for (int d = 0; d < 5; ++d) dw_s[t][d] = w[d] * inv - u;
        }
    }
    if (wv >= 2) {
#pragma unroll
        for (int rtl = 0; rtl < 2; ++rtl) {
            int vr0 = (wv * 2 + rtl - 4) * 16 + kg * 4;
#pragma unroll
            for (int ct = 0; ct < 3; ++ct) {
                int j = ct * 16 + a;
#pragma unroll
                for (int reg = 0; reg < 4; ++reg) {
                    if (j >= 2 && j < 38) k_s[vr0 + reg][j] = acc[rtl][ct][reg];
                }
            }
        }
    }
    __syncthreads();
    if (wv >= 2) {
#pragma unroll
        for (int rtl = 0; rtl < 2; ++rtl) {
            int vr0 = (wv * 2 + rtl - 4) * 16 + kg * 4;
#pragma unroll
            for (int reg = 0; reg < 4; ++reg) {
                float s = 0.f;
#pragma unroll
                for (int ct = 0; ct < 3; ++ct) {
                    int j = ct * 16 + a;
                    if (j >= 4 && j < 36) s += acc[rtl][ct][reg] * u_s[j - 2];
                }
                s += __shfl_xor(s, 1);
                s += __shfl_xor(s, 2);
                s += __shfl_xor(s, 4);
                s += __shfl_xor(s, 8);
                if (a == 0) red_s[vr0 + reg] = s;
            }
        }
    }
    {
        int mm = t & 31;
        int cq = t >> 5;
#pragma unroll
        for (int it = 0; it < 8; ++it) {
            int c = it * 8 + cq;
            float xc = 0.f;
#pragma unroll
            for (int o = -2; o <= 2; ++o)
                xc += k_s[c][mm - o + 4] * dw_s[mm - o + 2][o + 2];
            XC[(size_t)(hb * 64 + c) * LL + l0 + mm] = xc;
        }
    }
    __syncthreads();
    if (t < 64)
        Spart[((size_t)hb * 64 + blockIdx.y) * 64 + t] = red_s[t];
}

// ---------------------------------------------------------------------------
// Kernel D: x = inp + xcorr + S; channel attention -> gate; write XG.
// grid (B, 32), block 512 (8 waves).  [R18-verbatim]
__global__ __launch_bounds__(512) void kD(const float* __restrict__ inp,
                                          const float* __restrict__ hidden,
                                          const float* __restrict__ XC,
                                          const float* __restrict__ Spart,
                                          const float* __restrict__ w1T,
                                          const float* __restrict__ b1,
                                          const float* __restrict__ w2,
                                          const float* __restrict__ b2,
                                          float* __restrict__ XG) {
    int b = blockIdx.x;
    int m0 = blockIdx.y * 64;
    __shared__ float S2_s[256];
    __shared__ float partial[8][64][9];
    int t = threadIdx.x;
    int m = t & 63;
    int wv = t >> 6;
    if (t < 256) {
        int hb = (t >> 6) * 8 + b;
        float s = 0.f;
#pragma unroll
        for (int q = 0; q < 64; ++q)
            s += Spart[((size_t)hb * 64 + q) * 64 + (t & 63)];
        S2_s[t] = s;
    }
    __syncthreads();
    float xr[4][8];
    int cb = __builtin_amdgcn_readfirstlane(wv * 8);
#pragma unroll
    for (int h = 0; h < 4; ++h) {
#pragma unroll
        for (int cc = 0; cc < 8; ++cc) {
            int c = cb + cc;
            size_t idx = (size_t)((h * 8 + b) * 64 + c) * LL + m0 + m;
            xr[h][cc] = inp[idx] + XC[idx] + S2_s[h * 64 + c];
        }
    }
    float acc2[8] = {};
#pragma unroll
    for (int h = 0; h < 4; ++h) {
#pragma unroll
        for (int cc = 0; cc < 8; ++cc) {
            const float* wp = w1T + (h * 64 + cb + cc) * 8;
            float xv = xr[h][cc];
#pragma unroll
            for (int o = 0; o < 8; ++o) acc2[o] += wp[o] * xv;
        }
    }
#pragma unroll
    for (int i = 0; i < 8; ++i) {
        const float* wp = w1T + (256 + cb + i) * 8;
        float xv = hidden[(size_t)(b * 64 + cb + i) * LL + m0 + m];
#pragma unroll
        for (int o = 0; o < 8; ++o) acc2[o] += wp[o] * xv;
    }
#pragma unroll
    for (int o = 0; o < 8; ++o) partial[wv][m][o] = acc2[o];
    __syncthreads();
    float a[8];
#pragma unroll
    for (int o = 0; o < 8; ++o) {
        float v = b1[o];
#pragma unroll
        for (int p = 0; p < 8; ++p) v += partial[p][m][o];
        a[o] = fmaxf(v, 0.f);
    }
#pragma unroll
    for (int h = 0; h < 4; ++h) {
#pragma unroll
        for (int cc = 0; cc < 8; ++cc) {
            int ch = h * 64 + cb + cc;
            const float* wp = w2 + ch * 8;
            float g = b2[ch];
#pragma unroll
            for (int o = 0; o < 8; ++o) g += wp[o] * a[o];
            float gate = 1.f / (1.f + __expf(-g));
            XG[(size_t)(b * 256 + ch) * LL + m0 + m] = xr[h][cc] * gate;
        }
    }
}

// ---------------------------------------------------------------------------
// kConvM: conv1 (256 -> 64) + folded BN + ReLU via bf16 MFMA.
// grid (B, 128), block 256 (4 waves), l-tile 16.  [R18-verbatim]
__global__ __launch_bounds__(256) void kConvM(const float* __restrict__ XG,
                                              const ushort_t* __restrict__ wEb,
                                              const float* __restrict__ biasE,
                                              float* __restrict__ Y1) {
    int b = blockIdx.x;
    int l0 = blockIdx.y * 16;
    __shared__ ushort_t xts[2][18][CHP];
    __shared__ float bias_s[64];
    int t = threadIdx.x;
    if (t < 64) bias_s[t] = biasE[t];
    for (int q = t; q < 18 * 64; q += 256) {
        int row = q % 18;
        int ch0 = (q / 18) * 4;
        int l = l0 - 1 + row;
        bool v = (l >= 0 && l < LL);
        unsigned hp[2], lp[2];
#pragma unroll
        for (int p = 0; p < 2; ++p) {
            unsigned h2 = 0, l2 = 0;
#pragma unroll
            for (int i = 0; i < 2; ++i) {
                int ch = ch0 + p * 2 + i;
                float x = v ? XG[(size_t)(b * 256 + ch) * LL + l] : 0.f;
                ushort_t hi = f2bf(x);
                ushort_t lo = f2bf(x - bf2f(hi));
                h2 |= ((unsigned)hi) << (16 * i);
                l2 |= ((unsigned)lo) << (16 * i);
            }
            hp[p] = h2; lp[p] = l2;
        }
        *(unsigned*)&xts[0][row][ch0] = hp[0];
        *(unsigned*)&xts[0][row][ch0 + 2] = hp[1];
        *(unsigned*)&xts[1][row][ch0] = lp[0];
        *(unsigned*)&xts[1][row][ch0 + 2] = lp[1];
    }
    __syncthreads();
    int lane = t & 63;
    int wid = t >> 6;
    int a = lane & 15;
    int kg = lane >> 4;
    f32x4 acc = {};
    union U8 { unsigned u[4]; short8 s; };
#pragma unroll 4
    for (int ks = 0; ks < 24; ++ks) {
        int tap = ks >> 3;
        int ch0 = ((ks & 7) << 5) + (kg << 3);
        const ushort_t* ap = wEb + ((((size_t)wid * 24 + ks) * 64 + lane) << 3);
        short8 afr = *(const short8*)ap;
        int row = a + tap;
        const ushort_t* xh = &xts[0][row][ch0];
        const ushort_t* xl = &xts[1][row][ch0];
        U8 bh, bl;
#pragma unroll
        for (int qq = 0; qq < 4; ++qq) {
            bh.u[qq] = *(const unsigned*)(xh + 2 * qq);
            bl.u[qq] = *(const unsigned*)(xl + 2 * qq);
        }
        acc = __builtin_amdgcn_mfma_f32_16x16x32_bf16(afr, bh.s, acc, 0, 0, 0);
        acc = __builtin_amdgcn_mfma_f32_16x16x32_bf16(afr, bl.s, acc, 0, 0, 0);
    }
    {
        int m = a;
#pragma unroll
        for (int reg = 0; reg < 4; ++reg) {
            int r = wid * 16 + kg * 4 + reg;
            float y = acc[reg] + bias_s[r];
            Y1[(size_t)(b * 64 + r) * LL + l0 + m] = fmaxf(y, 0.f);
        }
    }
}

// ---------------------------------------------------------------------------
// kCM2: conv2 (64 -> 64) + folded BN + ReLU via bf16 MFMA.
// grid (B, 128), block 256 (4 waves), l-tile 16.  [R18-verbatim]
__global__ __launch_bounds__(256) void kCM2(const float* __restrict__ Y1,
                                            const ushort_t* __restrict__ wFb,
                                            const float* __restrict__ biasF,
                                            float* __restrict__ out) {
    int b = blockIdx.x;
    int l0 = blockIdx.y * 16;
    __shared__ ushort_t yts[2][18][70];
    __shared__ float bias_s[64];
    int t = threadIdx.x;
    if (t < 64) bias_s[t] = biasF[t];
    for (int q = t; q < 18 * 16; q += 256) {
        int row = q % 18;
        int c0 = (q / 18) * 4;
        int l = l0 - 1 + row;
        bool v = (l >= 0 && l < LL);
        unsigned hp[2], lp[2];
#pragma unroll
        for (int p = 0; p < 2; ++p) {
            unsigned h2 = 0, l2 = 0;
#pragma unroll
            for (int i = 0; i < 2; ++i) {
                int c = c0 + p * 2 + i;
                float x = v ? Y1[(size_t)(b * 64 + c) * LL + l] : 0.f;
                ushort_t hi = f2bf(x);
                ushort_t lo = f2bf(x - bf2f(hi));
                h2 |= ((unsigned)hi) << (16 * i);
                l2 |= ((unsigned)lo) << (16 * i);
            }
            hp[p] = h2; lp[p] = l2;
        }
        *(unsigned*)&yts[0][row][c0] = hp[0];
        *(unsigned*)&yts[0][row][c0 + 2] = hp[1];
        *(unsigned*)&yts[1][row][c0] = lp[0];
        *(unsigned*)&yts[1][row][c0 + 2] = lp[1];
    }
    __syncthreads();
    int lane = t & 63;
    int wid = t >> 6;
    int a = lane & 15;
    int kg = lane >> 4;
    f32x4 acc = {};
    union U8 { unsigned u[4]; short8 s; };
#pragma unroll
    for (int ks = 0; ks < 6; ++ks) {
        int tap = ks >> 1;
        int c0 = ((ks & 1) << 5) + (kg << 3);
        const ushort_t* ap = wFb + ((((size_t)wid * 6 + ks) * 64 + lane) << 3);
        short8 afr = *(const short8*)ap;
        int s = a + tap;
        const ushort_t* yh = &yts[0][s][c0];
        const ushort_t* yl = &yts[1][s][c0];
        U8 bh, bl;
#pragma unroll
        for (int qq = 0; qq < 4; ++qq) {
            bh.u[qq] = *(const unsigned*)(yh + 2 * qq);
            bl.u[qq] = *(const unsigned*)(yl + 2 * qq);
        }
        acc = __builtin_amdgcn_mfma_f32_16x16x32_bf16(afr, bh.s, acc, 0, 0, 0);
        acc = __builtin_amdgcn_mfma_f32_16x16x32_bf16(afr, bl.s, acc, 0, 0, 0);
    }
    {
        int m = a;
#pragma unroll
        for (int reg = 0; reg < 4; ++reg) {
            int r = wid * 16 + kg * 4 + reg;
            float y = acc[reg] + bias_s[r];
            out[(size_t)(b * 64 + r) * LL + l0 + m] = fmaxf(y, 0.f);
        }
    }
}

// ---------------------------------------------------------------------------
extern "C" void kernel_launch(void* const* d_in, const int* in_sizes, int n_in,
                              void* d_out, int out_size, void* d_ws, size_t ws_size,
                              hipStream_t stream) {
    (void)in_sizes; (void)n_in; (void)out_size; (void)ws_size;
    const float* inp    = (const float*)d_in[0];
    const float* hidden = (const float*)d_in[1];
    const float* key_w  = (const float*)d_in[2];
    const float* value_w= (const float*)d_in[3];
    const float* ca_w1  = (const float*)d_in[4];
    const float* ca_b1  = (const float*)d_in[5];
    const float* ca_w2  = (const float*)d_in[6];
    const float* ca_b2  = (const float*)d_in[7];
    const float* pw1    = (const float*)d_in[8];
    const float* bn1_g  = (const float*)d_in[9];
    const float* bn1_b  = (const float*)d_in[10];
    const float* bn1_m  = (const float*)d_in[11];
    const float* bn1_v  = (const float*)d_in[12];
    const float* pw2    = (const float*)d_in[13];
    const float* bn2_g  = (const float*)d_in[14];
    const float* bn2_b  = (const float*)d_in[15];
    const float* bn2_m  = (const float*)d_in[16];
    const float* bn2_v  = (const float*)d_in[17];

    float* ws = (float*)d_ws;
    const size_t KV = (size_t)HH * BB * CC * LL;     // 4,194,304 floats
    float* XG = ws;
    float* XC = ws + KV;                             // banded correction
    float* Spart = ws + 2 * KV;                      // 32*64*64 = 131072
    float* w1T   = Spart + 131072;                   // 2560
    float* biasE = w1T + 2560;                       // 64
    float* biasF = biasE + 64;                       // 64
    ushort_t* wEb = (ushort_t*)(biasF + 64);         // 49152 bf16
    ushort_t* wFb = (ushort_t*)(biasF + 64 + 24576); // 12288 bf16
    float* Y1 = XC;   // alias: XC dead after kD

    kABC<<<dim3(33, 64), 256, 0, stream>>>(inp, key_w, value_w, hidden,
                                           XC, Spart,
                                           pw1, bn1_g, bn1_m, bn1_v, bn1_b,
                                           pw2, bn2_g, bn2_m, bn2_v, bn2_b,
                                           ca_w1, wEb, wFb, biasE, biasF, w1T);
    kD<<<dim3(BB, LL / 64), 512, 0, stream>>>(inp, hidden, XC, Spart,
                                              w1T, ca_b1, ca_w2, ca_b2, XG);
    kConvM<<<dim3(BB, 128), 256, 0, stream>>>(XG, wEb, biasE, Y1);
    kCM2<<<dim3(BB, 128), 256, 0, stream>>>(Y1, wFb, biasF, (float*)d_out);
}